// Round 13
// baseline (296.049 us; speedup 1.0000x reference)
//
#include <hip/hip_runtime.h>
#include <hip/hip_bf16.h>

// Problem constants
#define MROWS 4096
#define TSTEPS 100
#define EMB 64
#define HID 128
#define GATES 512        // 4*HID
#define KTOT 192         // EMB + HID
#define ROWS_PB 32       // rows per block (one direction)
#define SROW 200         // padded A-panel row stride in f16 elems (400B, 16B aligned)
#define PSTR 520         // pooled-tile row stride in f16 elems (32x520x2 = 33280 B)

typedef _Float16 half8 __attribute__((ext_vector_type(8)));
typedef _Float16 half4v __attribute__((ext_vector_type(4)));
typedef float f32x4 __attribute__((ext_vector_type(4)));

#define LOG2E  1.44269504f
#define LOG2E2 2.88539008f

__device__ __forceinline__ float rcpf(float x) { return __builtin_amdgcn_rcpf(x); }
__device__ __forceinline__ float ex2(float x) { return __builtin_amdgcn_exp2f(x); }

// ---------------------------------------------------------------------------
// Kernel 1 (merged prep), grid 336 x 256:
//  blocks 0..255  : scores = softmax(relu(obs @ attn_W + attn_b)) (r1 proven)
//  blocks 256..271: enc_W -> MFMA-B-fragment-ordered f16 table (r11 proven)
//  blocks 272..335: zero pacc (2 MB); block 272 also zeroes flags
// ---------------------------------------------------------------------------
__global__ void prep_kernel(const float* __restrict__ obs,
                            const float* __restrict__ attn_W,
                            const float* __restrict__ attn_b,
                            float* __restrict__ scores,
                            const float* __restrict__ enc_W,
                            _Float16* __restrict__ frag,
                            float* __restrict__ pacc,
                            int* __restrict__ flags) {
    const int tid = threadIdx.x;     // 256
    if (blockIdx.x < 256) {
        const int row = blockIdx.x;
        __shared__ float obs_s[128];
        __shared__ float red[128];

        if (tid < 128) obs_s[tid] = obs[row * 128 + tid];
        __syncthreads();

        float s = -1e30f;
        if (tid < 100) {
            float a = attn_b[tid];
            #pragma unroll 4
            for (int k = 0; k < 128; k++) a += obs_s[k] * attn_W[k * 100 + tid];
            s = fmaxf(a, 0.f);
        }
        if (tid < 128) red[tid] = s;
        __syncthreads();
        for (int off = 64; off > 0; off >>= 1) {
            if (tid < off) red[tid] = fmaxf(red[tid], red[tid + off]);
            __syncthreads();
        }
        const float m = red[0];
        __syncthreads();
        const float e = (tid < 100) ? __expf(s - m) : 0.f;
        if (tid < 128) red[tid] = e;
        __syncthreads();
        for (int off = 64; off > 0; off >>= 1) {
            if (tid < off) red[tid] += red[tid + off];
            __syncthreads();
        }
        const float inv = __fdividef(1.f, red[0]);
        if (tid < 100) scores[row * 100 + tid] = e * inv;
    } else if (blockIdx.x < 272) {
        const int pb = blockIdx.x - 256;   // 0..15 -> K rows [pb*64, pb*64+64)
        __shared__ float tile[64][132];
        #pragma unroll
        for (int i = 0; i < 32; i++) {
            const int idx = i * 256 + tid;
            const int rr = idx >> 7, ccol = idx & 127;
            tile[rr][ccol] = enc_W[(pb * 64 + rr) * 128 + ccol];
        }
        __syncthreads();
        // 16 (tile,itl) pairs; 16 threads/pair; each thread emits 4 lanes
        const int pair = tid >> 4;        // 0..15
        const int tl = pair >> 1;         // 0..7
        const int itl = pair & 1;
        const int it = pb * 2 + itl;      // global K/32 chunk
        const int sub = tid & 15;
        #pragma unroll
        for (int li = 0; li < 4; li++) {
            const int l = sub * 4 + li;
            const int c = tl * 16 + (l & 15);
            const int kb = itl * 32 + (l >> 4) * 8;
            half8 v;
            #pragma unroll
            for (int j = 0; j < 8; j++) v[j] = (_Float16)tile[kb + j][c];
            *(half8*)(frag + (((long)(tl * 32 + it)) * 64 + l) * 8) = v;
        }
    } else {
        const int z = blockIdx.x - 272;   // 0..63
        const float4 zero = {0.f, 0.f, 0.f, 0.f};
        #pragma unroll
        for (int i = 0; i < 8; i++) {
            *(float4*)(pacc + (long)z * 8192 + (i * 256 + tid) * 4) = zero;
        }
        if (blockIdx.x == 272 && tid < 128) flags[tid] = 0;
    }
}

// ---------------------------------------------------------------------------
// Kernel 2: persistent bidirectional LSTM + fused partial encoder tail +
// last-arriver output combine (atomic protocol proven r11/r12).
// 256 blocks x 512 thr, 32 rows/block, 1 block/CU, weights in VGPRs.
// MFMA order: ki-outer interleaved across both row-tiles (r10-proven; the
// r12 per-row-tile chain split regressed 223.5 -> 235.4 us).
// NOTE: launch_bounds(512,2) = 256-VGPR budget. (512,4) forces spill of the
// 96-VGPR B fragments -> 2.5 GB scratch traffic (round-6 regression).
// ---------------------------------------------------------------------------
__launch_bounds__(512, 2)
__global__ void lstm_kernel(const float* __restrict__ lane_features,
                            const float* __restrict__ embed_W,
                            const float* __restrict__ embed_b,
                            const float* __restrict__ Wih_f,
                            const float* __restrict__ Whh_f,
                            const float* __restrict__ b_f,
                            const float* __restrict__ Wih_b,
                            const float* __restrict__ Whh_b,
                            const float* __restrict__ b_b,
                            const float* __restrict__ h0,
                            const float* __restrict__ c0,
                            const int*   __restrict__ mask,
                            const float* __restrict__ scores,
                            const float* __restrict__ enc_b,
                            const _Float16* __restrict__ frag,
                            float* __restrict__ pacc,
                            int* __restrict__ flags,
                            float* __restrict__ out) {
    const int blk = blockIdx.x;
    const int d = blk >> 7;                     // 0 = fwd, 1 = bwd
    const int rowbase = (blk & 127) * ROWS_PB;
    const int tid = threadIdx.x;
    const int wave = tid >> 6;
    const int lane = tid & 63;
    const int lane16 = lane & 15;
    const int quad = lane >> 4;

    const float* Wih = d ? Wih_b : Wih_f;
    const float* Whh = d ? Whh_b : Whh_f;
    const float* bia = d ? b_b : b_f;

    // 38400-byte shared pool: panel (25600) + att_s (12800); reused at the
    // end as the 32x520-f16 pooled tile for the encoder tail.
    __shared__ __attribute__((aligned(16))) char smem[38400];
    auto panel = (_Float16 (*)[ROWS_PB][SROW])smem;          // panel[2][32][200]
    float (*att_s)[32] = (float (*)[32])(smem + 25600);      // att_s[100][32]
    _Float16* pool = (_Float16*)smem;                        // tail reuse

    // ---- Per-thread embed weights (columns cc..cc+3) ----
    const int erow = tid >> 4;                  // row this thread embeds
    const int cc = (tid & 15) * 4;
    float ew_r[4][4], eb_r[4];
    #pragma unroll
    for (int j = 0; j < 4; j++) {
        #pragma unroll
        for (int jj = 0; jj < 4; jj++) ew_r[j][jj] = embed_W[j * EMB + cc + jj];
    }
    #pragma unroll
    for (int jj = 0; jj < 4; jj++) eb_r[jj] = embed_b[cc + jj];

    // ---- att gather (transposed): att_s[t][r] = scores[mask[r]*100 + t] ----
    {
        const int r = tid >> 4, tcol = tid & 15;
        const int mr = mask[rowbase + r];
        for (int t = tcol; t < 100; t += 16) att_s[t][r] = scores[mr * 100 + t];
    }

    // ---- Preload B fragments (MFMA B layout), exp2 scales folded ----
    const int unitg = wave * 16 + lane16;
    half8 Bf[24];   // [ct][ki] -> 96 VGPRs
    #pragma unroll
    for (int ct = 0; ct < 4; ct++) {
        const float scale = (ct == 2) ? LOG2E2 : LOG2E;
        const int col = ct * 128 + unitg;
        #pragma unroll
        for (int ki = 0; ki < 6; ki++) {
            half8 b;
            #pragma unroll
            for (int j = 0; j < 8; j++) {
                const int kk = ki * 32 + quad * 8 + j;
                const float w = (kk < EMB) ? Wih[kk * GATES + col]
                                           : Whh[(kk - EMB) * GATES + col];
                b[j] = (_Float16)(w * scale);
            }
            Bf[ct * 6 + ki] = b;
        }
    }
    // persistent bias accumulators (C operand of first MFMA in each chain)
    f32x4 biasacc[4];
    #pragma unroll
    for (int ct = 0; ct < 4; ct++) {
        const float bg = bia[ct * 128 + unitg] * ((ct == 2) ? LOG2E2 : LOG2E);
        biasacc[ct] = (f32x4){bg, bg, bg, bg};
    }

    // ---- Per-lane state: 8 (row,unit) pairs in C-layout ----
    float cst[8], mx[8], as[8], h0s[8], hl[8];
    const float cinit = c0[d * 128 + unitg];
    #pragma unroll
    for (int p = 0; p < 8; p++) {
        cst[p] = cinit; mx[p] = -1e30f; as[p] = 0.f; h0s[p] = 0.f; hl[p] = 0.f;
    }

    // ---- Init panel[0]: h part ----
    for (int idx = tid; idx < ROWS_PB * HID; idx += 512) {
        const int r = idx >> 7, u = idx & 127;
        panel[0][r][EMB + u] = (_Float16)h0[d * 128 + u];
    }

    // ---- Init panel[0]: x for first step ----
    {
        const int t0 = d ? (TSTEPS - 1) : 0;
        const float4 fv = *(const float4*)(lane_features + (long)(rowbase + erow) * 600 + 200 + 4 * t0);
        half4v hv;
        #pragma unroll
        for (int jj = 0; jj < 4; jj++) {
            float e = eb_r[jj] + fv.x * ew_r[0][jj] + fv.y * ew_r[1][jj]
                               + fv.z * ew_r[2][jj] + fv.w * ew_r[3][jj];
            hv[jj] = (_Float16)fmaxf(e, 0.f);
        }
        *(half4v*)&panel[0][erow][cc] = hv;
    }
    __syncthreads();

    // running feature pointer: first prefetch is step index 1 (t = d?98:1)
    const float* fptr = lane_features + (long)(rowbase + erow) * 600 + 200
                      + (d ? 4 * (TSTEPS - 2) : 4);
    const int fstep = d ? -4 : 4;

// One half-step: read panel[PB], write panel[1-PB]. SE = overall step index.
// ki-outer interleaved MFMA order (r10-proven schedule).
#define HALF_STEP(PB, SE)                                                      \
    {                                                                          \
        const int se = (SE);                                                   \
        const int t = d ? (TSTEPS - 1 - se) : se;                              \
        float4 fv;                                                             \
        if (se < TSTEPS - 1) { fv = *(const float4*)fptr; fptr += fstep; }     \
        const f32x4 awv0 = *(const f32x4*)&att_s[t][quad * 4];                 \
        const f32x4 awv1 = *(const f32x4*)&att_s[t][16 + quad * 4];            \
        f32x4 acc[2][4];                                                       \
        _Pragma("unroll")                                                      \
        for (int ki = 0; ki < 6; ki++) {                                       \
            const half8 a0 = *(const half8*)&panel[PB][lane16][ki * 32 + quad * 8];      \
            const half8 a1 = *(const half8*)&panel[PB][16 + lane16][ki * 32 + quad * 8]; \
            _Pragma("unroll")                                                  \
            for (int ct = 0; ct < 4; ct++) {                                   \
                acc[0][ct] = __builtin_amdgcn_mfma_f32_16x16x32_f16(           \
                    a0, Bf[ct * 6 + ki], (ki == 0) ? biasacc[ct] : acc[0][ct], 0, 0, 0); \
                acc[1][ct] = __builtin_amdgcn_mfma_f32_16x16x32_f16(           \
                    a1, Bf[ct * 6 + ki], (ki == 0) ? biasacc[ct] : acc[1][ct], 0, 0, 0); \
            }                                                                  \
        }                                                                      \
        _Pragma("unroll")                                                      \
        for (int rt = 0; rt < 2; rt++) {                                       \
            _Pragma("unroll")                                                  \
            for (int r = 0; r < 4; r++) {                                      \
                const int pp = rt * 4 + r;                                     \
                const int row_local = rt * 16 + quad * 4 + r;                  \
                const float gi = acc[rt][0][r];                                \
                const float gf = acc[rt][1][r];                                \
                const float gg = fminf(acc[rt][2][r], 80.f);                   \
                const float go = acc[rt][3][r];                                \
                const float Ei = ex2(-gi);                                     \
                const float Ef = ex2(-gf);                                     \
                const float Eg = ex2(gg);                                      \
                const float Eo = ex2(-go);                                     \
                const float sf = rcpf(1.f + Ef);                               \
                const float r1 = rcpf((1.f + Ei) * (Eg + 1.f));                \
                const float cn = sf * cst[pp] + (Eg - 1.f) * r1;               \
                const float Ec = ex2(fminf(cn * LOG2E2, 80.f));                \
                const float r2 = rcpf((1.f + Eo) * (Ec + 1.f));                \
                const float h = (Ec - 1.f) * r2;                               \
                cst[pp] = cn;                                                  \
                hl[pp] = h;                                                    \
                mx[pp] = fmaxf(mx[pp], h);                                     \
                as[pp] = fmaf((rt ? awv1 : awv0)[r], h, as[pp]);               \
                panel[1 - (PB)][row_local][EMB + unitg] = (_Float16)h;         \
            }                                                                  \
        }                                                                      \
        if (se == 0) {                                                         \
            _Pragma("unroll")                                                  \
            for (int pp = 0; pp < 8; pp++) h0s[pp] = hl[pp];                   \
        }                                                                      \
        if (se < TSTEPS - 1) {                                                 \
            half4v hv;                                                         \
            _Pragma("unroll")                                                  \
            for (int jj = 0; jj < 4; jj++) {                                   \
                float e = eb_r[jj] + fv.x * ew_r[0][jj] + fv.y * ew_r[1][jj]   \
                                   + fv.z * ew_r[2][jj] + fv.w * ew_r[3][jj];  \
                hv[jj] = (_Float16)fmaxf(e, 0.f);                              \
            }                                                                  \
            *(half4v*)&panel[1 - (PB)][erow][cc] = hv;                         \
        }                                                                      \
        __syncthreads();                                                       \
    }

    // ================= main recurrence (unrolled x2: p static) =============
    for (int s = 0; s < TSTEPS; s += 2) {
        HALF_STEP(0, s)
        HALF_STEP(1, s + 1)
    }
#undef HALF_STEP

    // ===== fused encoder tail =====
    // Stage pooled tile in reused LDS: pool[row 0..31][kloc 0..511], kloc =
    // seg*128 + unit, segs = front|back|max|attn (this direction's halves).
    #pragma unroll
    for (int pp = 0; pp < 8; pp++) {
        const int row_local = (pp >> 2) * 16 + quad * 4 + (pp & 3);
        const float fr = d ? hl[pp] : h0s[pp];
        const float bk = d ? h0s[pp] : hl[pp];
        pool[row_local * PSTR + 0 * 128 + unitg] = (_Float16)fr;
        pool[row_local * PSTR + 1 * 128 + unitg] = (_Float16)bk;
        pool[row_local * PSTR + 2 * 128 + unitg] = (_Float16)mx[pp];
        pool[row_local * PSTR + 3 * 128 + unitg] = (_Float16)as[pp];
    }
    __syncthreads();

    // Partial GEMM: C[32 x 16cols(tile=wave)] += pool(32x512) @ enc_W slice.
    // Global K-chunk for local chunk lc=(seg,c): itg = seg*8 + d*4 + c.
    f32x4 cacc0 = {0.f, 0.f, 0.f, 0.f}, cacc1 = {0.f, 0.f, 0.f, 0.f};
    const _Float16* fbase = frag + ((long)wave * 32) * 64 * 8 + lane * 8;
    #pragma unroll
    for (int lc = 0; lc < 16; lc++) {
        const int seg = lc >> 2, c = lc & 3;
        const int itg = seg * 8 + d * 4 + c;
        const half8 b  = *(const half8*)(fbase + (long)itg * 64 * 8);
        const half8 a0 = *(const half8*)&pool[lane16 * PSTR + lc * 32 + quad * 8];
        const half8 a1 = *(const half8*)&pool[(16 + lane16) * PSTR + lc * 32 + quad * 8];
        cacc0 = __builtin_amdgcn_mfma_f32_16x16x32_f16(a0, b, cacc0, 0, 0, 0);
        cacc1 = __builtin_amdgcn_mfma_f32_16x16x32_f16(a1, b, cacc1, 0, 0, 0);
    }

    // Accumulate partials via device-scope atomics (pacc zeroed by prep);
    // the last-arriving block of the (fwd,bwd) pair applies bias+relu -> out.
    const int col = wave * 16 + lane16;
    #pragma unroll
    for (int r = 0; r < 4; r++) {
        atomicAdd(&pacc[(long)(rowbase + quad * 4 + r) * 128 + col], cacc0[r]);
        atomicAdd(&pacc[(long)(rowbase + 16 + quad * 4 + r) * 128 + col], cacc1[r]);
    }
    __syncthreads();            // drains vmcnt: this block's atomics complete
    int* lf = (int*)smem;
    if (tid == 0) lf[0] = atomicAdd(&flags[blk & 127], 1);
    __syncthreads();
    if (lf[0] == 1) {
        // Partner's atomics completed before its flag increment; these
        // addresses were only ever written via device-coherent atomics and
        // never cached locally, so plain loads observe the full sums.
        const float bb = enc_b[col];
        #pragma unroll
        for (int r = 0; r < 4; r++) {
            const long i0 = (long)(rowbase + quad * 4 + r) * 128 + col;
            const long i1 = (long)(rowbase + 16 + quad * 4 + r) * 128 + col;
            out[i0] = fmaxf(pacc[i0] + bb, 0.f);
            out[i1] = fmaxf(pacc[i1] + bb, 0.f);
        }
    }
}

// ---------------------------------------------------------------------------
extern "C" void kernel_launch(void* const* d_in, const int* in_sizes, int n_in,
                              void* d_out, int out_size, void* d_ws, size_t ws_size,
                              hipStream_t stream) {
    const float* lane_features = (const float*)d_in[0];
    const float* obs_encoding  = (const float*)d_in[1];
    const float* embed_W = (const float*)d_in[2];
    const float* embed_b = (const float*)d_in[3];
    const float* attn_W  = (const float*)d_in[4];
    const float* attn_b  = (const float*)d_in[5];
    const float* Wih_f   = (const float*)d_in[6];
    const float* Whh_f   = (const float*)d_in[7];
    const float* b_f     = (const float*)d_in[8];
    const float* Wih_b   = (const float*)d_in[9];
    const float* Whh_b   = (const float*)d_in[10];
    const float* b_b     = (const float*)d_in[11];
    const float* h0      = (const float*)d_in[12];
    const float* c0      = (const float*)d_in[13];
    const float* enc_W   = (const float*)d_in[14];
    const float* enc_b   = (const float*)d_in[15];
    const int*   mask    = (const int*)d_in[16];

    float*     scores = (float*)d_ws;                           // 100 KB
    _Float16*  frag   = (_Float16*)((char*)d_ws + (128 << 10)); // 256 KB
    int*       flags  = (int*)((char*)d_ws + (448 << 10));      // 512 B
    float*     pacc   = (float*)((char*)d_ws + (512 << 10));    // 2 MB
    float*     out    = (float*)d_out;                          // 4096*128 f32

    prep_kernel<<<336, 256, 0, stream>>>(obs_encoding, attn_W, attn_b, scores,
                                         enc_W, frag, pacc, flags);
    lstm_kernel<<<256, 512, 0, stream>>>(lane_features, embed_W, embed_b,
                                         Wih_f, Whh_f, b_f, Wih_b, Whh_b, b_b,
                                         h0, c0, mask, scores, enc_b,
                                         frag, pacc, flags, out);
}

// Round 14
// 286.250 us; speedup vs baseline: 1.0342x; 1.0342x over previous
//
#include <hip/hip_runtime.h>
#include <hip/hip_bf16.h>

// Problem constants
#define MROWS 4096
#define TSTEPS 100
#define EMB 64
#define HID 128
#define GATES 512        // 4*HID
#define KTOT 192         // EMB + HID
#define ROWS_PB 32       // rows per block (one direction)
#define SROW 200         // padded A-panel row stride in f16 elems (400B, 16B aligned)
#define PSTR 520         // pooled-tile row stride in f16 elems (32x520x2 = 33280 B)

typedef _Float16 half8 __attribute__((ext_vector_type(8)));
typedef _Float16 half4v __attribute__((ext_vector_type(4)));
typedef float f32x4 __attribute__((ext_vector_type(4)));

#define LOG2E  1.44269504f
#define LOG2E2 2.88539008f

__device__ __forceinline__ float rcpf(float x) { return __builtin_amdgcn_rcpf(x); }
__device__ __forceinline__ float ex2(float x) { return __builtin_amdgcn_exp2f(x); }

// ---------------------------------------------------------------------------
// Kernel 1 (merged prep), grid 272 x 256:
//  blocks 0..255:  scores = softmax(relu(obs @ attn_W + attn_b)) (round-1 math)
//  blocks 256..271: enc_W (1024x128 f32) -> MFMA-B-fragment-ordered f16 table
//     frag[((tile*32 + it)*64 + lane)*8 + j] = enc_W[(it*32+(lane>>4)*8+j)*128
//                                                     + tile*16 + (lane&15)]
// ---------------------------------------------------------------------------
__global__ void prep_kernel(const float* __restrict__ obs,
                            const float* __restrict__ attn_W,
                            const float* __restrict__ attn_b,
                            float* __restrict__ scores,
                            const float* __restrict__ enc_W,
                            _Float16* __restrict__ frag) {
    const int tid = threadIdx.x;     // 256
    if (blockIdx.x < 256) {
        const int row = blockIdx.x;
        __shared__ float obs_s[128];
        __shared__ float red[128];

        if (tid < 128) obs_s[tid] = obs[row * 128 + tid];
        __syncthreads();

        float s = -1e30f;
        if (tid < 100) {
            float a = attn_b[tid];
            #pragma unroll 4
            for (int k = 0; k < 128; k++) a += obs_s[k] * attn_W[k * 100 + tid];
            s = fmaxf(a, 0.f);
        }
        if (tid < 128) red[tid] = s;
        __syncthreads();
        for (int off = 64; off > 0; off >>= 1) {
            if (tid < off) red[tid] = fmaxf(red[tid], red[tid + off]);
            __syncthreads();
        }
        const float m = red[0];
        __syncthreads();
        const float e = (tid < 100) ? __expf(s - m) : 0.f;
        if (tid < 128) red[tid] = e;
        __syncthreads();
        for (int off = 64; off > 0; off >>= 1) {
            if (tid < off) red[tid] += red[tid + off];
            __syncthreads();
        }
        const float inv = __fdividef(1.f, red[0]);
        if (tid < 100) scores[row * 100 + tid] = e * inv;
    } else {
        // fragment reorder: 256 (tile,it) pairs total, 16 per block
        const int pb = blockIdx.x - 256;        // 0..15
        const int pair = pb * 16 + (tid >> 4);  // 0..255
        const int tile = pair >> 5;             // 0..7 (16-col tile)
        const int it   = pair & 31;             // K/32 chunk
        const int sub  = tid & 15;              // handles 4 lanes
        #pragma unroll
        for (int li = 0; li < 4; li++) {
            const int l = sub * 4 + li;
            const int c = tile * 16 + (l & 15);
            const int kbase = it * 32 + (l >> 4) * 8;
            half8 v;
            #pragma unroll
            for (int j = 0; j < 8; j++) v[j] = (_Float16)enc_W[(kbase + j) * 128 + c];
            *(half8*)(frag + (((long)(tile * 32 + it)) * 64 + l) * 8) = v;
        }
    }
}

// ---------------------------------------------------------------------------
// Kernel 2: persistent bidirectional LSTM + fused partial encoder GEMM tail.
// 256 blocks x 512 thr, 32 rows/block, 1 block/CU, weights in VGPRs.
// Partials written to pacc[d] with PLAIN stores (fwd/bwd disjoint halves) —
// the r11-r13 atomicAdd tail cost ~13 us inside this kernel; reverted.
// NOTE: launch_bounds(512,2) = 256-VGPR budget. (512,4) forces spill of the
// 96-VGPR B fragments -> 2.5 GB scratch traffic (round-6 regression).
// MFMA order: ki-outer interleaved across both row-tiles (r10-proven).
// ---------------------------------------------------------------------------
__launch_bounds__(512, 2)
__global__ void lstm_kernel(const float* __restrict__ lane_features,
                            const float* __restrict__ embed_W,
                            const float* __restrict__ embed_b,
                            const float* __restrict__ Wih_f,
                            const float* __restrict__ Whh_f,
                            const float* __restrict__ b_f,
                            const float* __restrict__ Wih_b,
                            const float* __restrict__ Whh_b,
                            const float* __restrict__ b_b,
                            const float* __restrict__ h0,
                            const float* __restrict__ c0,
                            const int*   __restrict__ mask,
                            const float* __restrict__ scores,
                            const _Float16* __restrict__ frag,
                            float* __restrict__ pacc) {
    const int blk = blockIdx.x;
    const int d = blk >> 7;                     // 0 = fwd, 1 = bwd
    const int rowbase = (blk & 127) * ROWS_PB;
    const int tid = threadIdx.x;
    const int wave = tid >> 6;
    const int lane = tid & 63;
    const int lane16 = lane & 15;
    const int quad = lane >> 4;

    const float* Wih = d ? Wih_b : Wih_f;
    const float* Whh = d ? Whh_b : Whh_f;
    const float* bia = d ? b_b : b_f;

    // 38400-byte shared pool: panel (25600) + att_s (12800); reused at the
    // end as the 32x520-f16 pooled tile (33280 B) for the encoder tail.
    __shared__ __attribute__((aligned(16))) char smem[38400];
    auto panel = (_Float16 (*)[ROWS_PB][SROW])smem;          // panel[2][32][200]
    float (*att_s)[32] = (float (*)[32])(smem + 25600);      // att_s[100][32] (transposed)
    _Float16* pool = (_Float16*)smem;                        // tail reuse

    // ---- Per-thread embed weights (columns cc..cc+3) ----
    const int erow = tid >> 4;                  // row this thread embeds
    const int cc = (tid & 15) * 4;
    float ew_r[4][4], eb_r[4];
    #pragma unroll
    for (int j = 0; j < 4; j++) {
        #pragma unroll
        for (int jj = 0; jj < 4; jj++) ew_r[j][jj] = embed_W[j * EMB + cc + jj];
    }
    #pragma unroll
    for (int jj = 0; jj < 4; jj++) eb_r[jj] = embed_b[cc + jj];

    // ---- att gather (transposed): att_s[t][r] = scores[mask[r]*100 + t] ----
    {
        const int r = tid >> 4, tcol = tid & 15;
        const int mr = mask[rowbase + r];
        for (int t = tcol; t < 100; t += 16) att_s[t][r] = scores[mr * 100 + t];
    }

    // ---- Preload B fragments (MFMA B layout), exp2 scales folded ----
    const int unitg = wave * 16 + lane16;
    half8 Bf[24];   // [ct][ki] -> 96 VGPRs
    #pragma unroll
    for (int ct = 0; ct < 4; ct++) {
        const float scale = (ct == 2) ? LOG2E2 : LOG2E;
        const int col = ct * 128 + unitg;
        #pragma unroll
        for (int ki = 0; ki < 6; ki++) {
            half8 b;
            #pragma unroll
            for (int j = 0; j < 8; j++) {
                const int kk = ki * 32 + quad * 8 + j;
                const float w = (kk < EMB) ? Wih[kk * GATES + col]
                                           : Whh[(kk - EMB) * GATES + col];
                b[j] = (_Float16)(w * scale);
            }
            Bf[ct * 6 + ki] = b;
        }
    }
    // persistent bias accumulators (C operand of first MFMA in each chain)
    f32x4 biasacc[4];
    #pragma unroll
    for (int ct = 0; ct < 4; ct++) {
        const float bg = bia[ct * 128 + unitg] * ((ct == 2) ? LOG2E2 : LOG2E);
        biasacc[ct] = (f32x4){bg, bg, bg, bg};
    }

    // ---- Per-lane state: 8 (row,unit) pairs in C-layout ----
    float cst[8], mx[8], as[8], h0s[8], hl[8];
    const float cinit = c0[d * 128 + unitg];
    #pragma unroll
    for (int p = 0; p < 8; p++) {
        cst[p] = cinit; mx[p] = -1e30f; as[p] = 0.f; h0s[p] = 0.f; hl[p] = 0.f;
    }

    // ---- Init panel[0]: h part ----
    for (int idx = tid; idx < ROWS_PB * HID; idx += 512) {
        const int r = idx >> 7, u = idx & 127;
        panel[0][r][EMB + u] = (_Float16)h0[d * 128 + u];
    }

    // ---- Init panel[0]: x for first step ----
    {
        const int t0 = d ? (TSTEPS - 1) : 0;
        const float4 fv = *(const float4*)(lane_features + (long)(rowbase + erow) * 600 + 200 + 4 * t0);
        half4v hv;
        #pragma unroll
        for (int jj = 0; jj < 4; jj++) {
            float e = eb_r[jj] + fv.x * ew_r[0][jj] + fv.y * ew_r[1][jj]
                               + fv.z * ew_r[2][jj] + fv.w * ew_r[3][jj];
            hv[jj] = (_Float16)fmaxf(e, 0.f);
        }
        *(half4v*)&panel[0][erow][cc] = hv;
    }
    __syncthreads();

    // running feature pointer: first prefetch is step index 1 (t = d?98:1)
    const float* fptr = lane_features + (long)(rowbase + erow) * 600 + 200
                      + (d ? 4 * (TSTEPS - 2) : 4);
    const int fstep = d ? -4 : 4;

// One half-step: read panel[PB], write panel[1-PB]. SE = overall step index.
#define HALF_STEP(PB, SE)                                                      \
    {                                                                          \
        const int se = (SE);                                                   \
        const int t = d ? (TSTEPS - 1 - se) : se;                              \
        float4 fv;                                                             \
        if (se < TSTEPS - 1) { fv = *(const float4*)fptr; fptr += fstep; }     \
        const f32x4 awv0 = *(const f32x4*)&att_s[t][quad * 4];                 \
        const f32x4 awv1 = *(const f32x4*)&att_s[t][16 + quad * 4];            \
        f32x4 acc[2][4];                                                       \
        _Pragma("unroll")                                                      \
        for (int ki = 0; ki < 6; ki++) {                                       \
            const half8 a0 = *(const half8*)&panel[PB][lane16][ki * 32 + quad * 8];      \
            const half8 a1 = *(const half8*)&panel[PB][16 + lane16][ki * 32 + quad * 8]; \
            _Pragma("unroll")                                                  \
            for (int ct = 0; ct < 4; ct++) {                                   \
                if (ki == 0) {                                                 \
                    acc[0][ct] = __builtin_amdgcn_mfma_f32_16x16x32_f16(a0, Bf[ct * 6], biasacc[ct], 0, 0, 0); \
                    acc[1][ct] = __builtin_amdgcn_mfma_f32_16x16x32_f16(a1, Bf[ct * 6], biasacc[ct], 0, 0, 0); \
                } else {                                                       \
                    acc[0][ct] = __builtin_amdgcn_mfma_f32_16x16x32_f16(a0, Bf[ct * 6 + ki], acc[0][ct], 0, 0, 0); \
                    acc[1][ct] = __builtin_amdgcn_mfma_f32_16x16x32_f16(a1, Bf[ct * 6 + ki], acc[1][ct], 0, 0, 0); \
                }                                                              \
            }                                                                  \
        }                                                                      \
        _Pragma("unroll")                                                      \
        for (int rt = 0; rt < 2; rt++) {                                       \
            _Pragma("unroll")                                                  \
            for (int r = 0; r < 4; r++) {                                      \
                const int pp = rt * 4 + r;                                     \
                const int row_local = rt * 16 + quad * 4 + r;                  \
                const float gi = acc[rt][0][r];                                \
                const float gf = acc[rt][1][r];                                \
                const float gg = fminf(acc[rt][2][r], 80.f);                   \
                const float go = acc[rt][3][r];                                \
                const float Ei = ex2(-gi);                                     \
                const float Ef = ex2(-gf);                                     \
                const float Eg = ex2(gg);                                      \
                const float Eo = ex2(-go);                                     \
                const float sf = rcpf(1.f + Ef);                               \
                const float r1 = rcpf((1.f + Ei) * (Eg + 1.f));                \
                const float cn = sf * cst[pp] + (Eg - 1.f) * r1;               \
                const float Ec = ex2(fminf(cn * LOG2E2, 80.f));                \
                const float r2 = rcpf((1.f + Eo) * (Ec + 1.f));                \
                const float h = (Ec - 1.f) * r2;                               \
                cst[pp] = cn;                                                  \
                hl[pp] = h;                                                    \
                mx[pp] = fmaxf(mx[pp], h);                                     \
                as[pp] = fmaf((rt ? awv1 : awv0)[r], h, as[pp]);               \
                panel[1 - (PB)][row_local][EMB + unitg] = (_Float16)h;         \
            }                                                                  \
        }                                                                      \
        if (se == 0) {                                                         \
            _Pragma("unroll")                                                  \
            for (int pp = 0; pp < 8; pp++) h0s[pp] = hl[pp];                   \
        }                                                                      \
        if (se < TSTEPS - 1) {                                                 \
            half4v hv;                                                         \
            _Pragma("unroll")                                                  \
            for (int jj = 0; jj < 4; jj++) {                                   \
                float e = eb_r[jj] + fv.x * ew_r[0][jj] + fv.y * ew_r[1][jj]   \
                                   + fv.z * ew_r[2][jj] + fv.w * ew_r[3][jj];  \
                hv[jj] = (_Float16)fmaxf(e, 0.f);                              \
            }                                                                  \
            *(half4v*)&panel[1 - (PB)][erow][cc] = hv;                         \
        }                                                                      \
        __syncthreads();                                                       \
    }

    // ================= main recurrence (unrolled x2: p static) =============
    for (int s = 0; s < TSTEPS; s += 2) {
        HALF_STEP(0, s)
        HALF_STEP(1, s + 1)
    }
#undef HALF_STEP

    // ===== fused encoder tail =====
    // Stage pooled tile in reused LDS: pool[row 0..31][kloc 0..511], kloc =
    // seg*128 + unit, segs = front|back|max|attn (this direction's halves).
    #pragma unroll
    for (int pp = 0; pp < 8; pp++) {
        const int row_local = (pp >> 2) * 16 + quad * 4 + (pp & 3);
        const float fr = d ? hl[pp] : h0s[pp];
        const float bk = d ? h0s[pp] : hl[pp];
        pool[row_local * PSTR + 0 * 128 + unitg] = (_Float16)fr;
        pool[row_local * PSTR + 1 * 128 + unitg] = (_Float16)bk;
        pool[row_local * PSTR + 2 * 128 + unitg] = (_Float16)mx[pp];
        pool[row_local * PSTR + 3 * 128 + unitg] = (_Float16)as[pp];
    }
    __syncthreads();

    // Partial GEMM: C[32 x 16cols(tile=wave)] += pool(32x512) @ enc_W slice.
    // Global K-chunk for local chunk lc=(seg,c): itg = seg*8 + d*4 + c.
    f32x4 cacc0 = {0.f, 0.f, 0.f, 0.f}, cacc1 = {0.f, 0.f, 0.f, 0.f};
    const _Float16* fbase = frag + ((long)wave * 32) * 64 * 8 + lane * 8;
    #pragma unroll
    for (int lc = 0; lc < 16; lc++) {
        const int seg = lc >> 2, c = lc & 3;
        const int itg = seg * 8 + d * 4 + c;
        const half8 b  = *(const half8*)(fbase + (long)itg * 64 * 8);
        const half8 a0 = *(const half8*)&pool[lane16 * PSTR + lc * 32 + quad * 8];
        const half8 a1 = *(const half8*)&pool[(16 + lane16) * PSTR + lc * 32 + quad * 8];
        cacc0 = __builtin_amdgcn_mfma_f32_16x16x32_f16(a0, b, cacc0, 0, 0, 0);
        cacc1 = __builtin_amdgcn_mfma_f32_16x16x32_f16(a1, b, cacc1, 0, 0, 0);
    }
    float* pacc_d = pacc + (long)d * MROWS * 128;
    #pragma unroll
    for (int r = 0; r < 4; r++) {
        pacc_d[(long)(rowbase + quad * 4 + r) * 128 + wave * 16 + lane16]      = cacc0[r];
        pacc_d[(long)(rowbase + 16 + quad * 4 + r) * 128 + wave * 16 + lane16] = cacc1[r];
    }
}

// ---------------------------------------------------------------------------
// Kernel 3: out = relu(paccA + paccB + enc_b)   (4096x128)
// ---------------------------------------------------------------------------
__global__ void final_kernel(const float* __restrict__ pacc,
                             const float* __restrict__ enc_b,
                             float* __restrict__ out) {
    const int idx = (blockIdx.x * 256 + threadIdx.x) * 4;   // 512 blocks
    const float4 a = *(const float4*)(pacc + idx);
    const float4 b = *(const float4*)(pacc + (long)MROWS * 128 + idx);
    const float4 bb = *(const float4*)(enc_b + (idx & 127));
    float4 o;
    o.x = fmaxf(a.x + b.x + bb.x, 0.f);
    o.y = fmaxf(a.y + b.y + bb.y, 0.f);
    o.z = fmaxf(a.z + b.z + bb.z, 0.f);
    o.w = fmaxf(a.w + b.w + bb.w, 0.f);
    *(float4*)(out + idx) = o;
}

// ---------------------------------------------------------------------------
extern "C" void kernel_launch(void* const* d_in, const int* in_sizes, int n_in,
                              void* d_out, int out_size, void* d_ws, size_t ws_size,
                              hipStream_t stream) {
    const float* lane_features = (const float*)d_in[0];
    const float* obs_encoding  = (const float*)d_in[1];
    const float* embed_W = (const float*)d_in[2];
    const float* embed_b = (const float*)d_in[3];
    const float* attn_W  = (const float*)d_in[4];
    const float* attn_b  = (const float*)d_in[5];
    const float* Wih_f   = (const float*)d_in[6];
    const float* Whh_f   = (const float*)d_in[7];
    const float* b_f     = (const float*)d_in[8];
    const float* Wih_b   = (const float*)d_in[9];
    const float* Whh_b   = (const float*)d_in[10];
    const float* b_b     = (const float*)d_in[11];
    const float* h0      = (const float*)d_in[12];
    const float* c0      = (const float*)d_in[13];
    const float* enc_W   = (const float*)d_in[14];
    const float* enc_b   = (const float*)d_in[15];
    const int*   mask    = (const int*)d_in[16];

    float*     scores = (float*)d_ws;                            // 100 KB
    _Float16*  frag   = (_Float16*)((char*)d_ws + (128 << 10));  // 256 KB
    float*     pacc   = (float*)((char*)d_ws + (512 << 10));     // 2 x 2 MB
    float*     out    = (float*)d_out;                           // 4096*128 f32

    prep_kernel<<<272, 256, 0, stream>>>(obs_encoding, attn_W, attn_b, scores,
                                         enc_W, frag);
    lstm_kernel<<<256, 512, 0, stream>>>(lane_features, embed_W, embed_b,
                                         Wih_f, Whh_f, b_f, Wih_b, Whh_b, b_b,
                                         h0, c0, mask, scores, frag, pacc);
    final_kernel<<<512, 256, 0, stream>>>(pacc, enc_b, out);
}